// Round 6
// baseline (891.112 us; speedup 1.0000x reference)
//
#include <hip/hip_runtime.h>
#include <hip/hip_fp16.h>

#define N_NODES    100000
#define N_EDGES    3200000
#define IN_DIM     128
#define EMB        32
#define NUM_GRAPHS 256

#define NB         1563      // 64-node buckets = ceil(N_NODES/64)
#define NBP        2048      // padded bucket count (pow2, for scan/LDS)
#define F1_EPB     8192      // edges per fill block
#define F1_BLOCKS  391       // ceil(N_EDGES / F1_EPB)
#define XW_BLOCKS  1563      // ceil(N_NODES/64) rows; also covers 1563*2048 edges
#define XW_EPB     2048      // edges deg-counted per xw block

typedef _Float16 half8 __attribute__((ext_vector_type(8)));
typedef float floatx4 __attribute__((ext_vector_type(4)));

// ---------------------------------------------------------------------------
// Kernel 1: xw = x @ W1 -> fp16 via MFMA 16x16x32_f16 (one wave = 16 rows).
// Also: exact in-degree histogram (global atomics, hidden behind the x stream)
// and chist zero-init (block 0).  deg must be zeroed before this kernel.
// ---------------------------------------------------------------------------
__global__ __launch_bounds__(256) void k_xw(const float* __restrict__ x,
                                            const float* __restrict__ W1,
                                            const int* __restrict__ ei,
                                            __half* __restrict__ xwh,
                                            int* __restrict__ deg,
                                            int* __restrict__ chist) {
    if (blockIdx.x == 0)
        for (int i = threadIdx.x; i < NBP; i += 256) chist[i] = 0;
    // degree slice: this block counts edges [blockIdx*XW_EPB, +XW_EPB)
    {
        int e0 = blockIdx.x * XW_EPB;
        for (int k = threadIdx.x; k < XW_EPB; k += 256) {
            int e = e0 + k;
            if (e < N_EDGES) atomicAdd(&deg[ei[N_EDGES + e]], 1);
        }
    }
    __shared__ _Float16 Wh[IN_DIM * EMB];   // 8 KB
    for (int i = threadIdx.x; i < IN_DIM * EMB; i += 256)
        Wh[i] = (_Float16)W1[i];
    __syncthreads();
    int wave = threadIdx.x >> 6;
    int lane = threadIdx.x & 63;
    int m = lane & 15, quad = lane >> 4;
    int row0 = (blockIdx.x * 4 + wave) * 16;
    if (row0 >= N_NODES) return;
    half8 bfrag[2][4];
#pragma unroll
    for (int nt = 0; nt < 2; ++nt)
#pragma unroll
        for (int ks = 0; ks < 4; ++ks)
#pragma unroll
            for (int j = 0; j < 8; ++j)
                bfrag[nt][ks][j] = Wh[(ks * 32 + quad * 8 + j) * EMB + nt * 16 + m];
    const float* xr = x + (size_t)(row0 + m) * IN_DIM + quad * 8;
    floatx4 c0 = {0.f, 0.f, 0.f, 0.f}, c1 = {0.f, 0.f, 0.f, 0.f};
#pragma unroll
    for (int ks = 0; ks < 4; ++ks) {
        float4 a0 = *(const float4*)(xr + ks * 32);
        float4 a1 = *(const float4*)(xr + ks * 32 + 4);
        half8 af;
        af[0] = (_Float16)a0.x; af[1] = (_Float16)a0.y;
        af[2] = (_Float16)a0.z; af[3] = (_Float16)a0.w;
        af[4] = (_Float16)a1.x; af[5] = (_Float16)a1.y;
        af[6] = (_Float16)a1.z; af[7] = (_Float16)a1.w;
        c0 = __builtin_amdgcn_mfma_f32_16x16x32_f16(af, bfrag[0][ks], c0, 0, 0, 0);
        c1 = __builtin_amdgcn_mfma_f32_16x16x32_f16(af, bfrag[1][ks], c1, 0, 0, 0);
    }
#pragma unroll
    for (int r = 0; r < 4; ++r) {
        int ro = row0 + quad * 4 + r;
        xwh[(size_t)ro * EMB + m]      = __float2half(c0[r]);
        xwh[(size_t)ro * EMB + 16 + m] = __float2half(c1[r]);
    }
}

// ---------------------------------------------------------------------------
// Scale: dinv[i] = rsqrt(deg+1); xwh[i] *= dinv[i] (in place);
// chist[bucket] += sum(deg of this block's 8 nodes)  (bucket = node>>6).
// Grid 12500 x 256 (8 rows x 32 cols); 12500*8 == N_NODES exactly.
// ---------------------------------------------------------------------------
__global__ __launch_bounds__(256) void k_scale(const int* __restrict__ deg,
                                               __half* __restrict__ xwh,
                                               float* __restrict__ dinv,
                                               int* __restrict__ chist) {
    __shared__ int degi[8];
    int r = threadIdx.x >> 5, c = threadIdx.x & 31;
    int node = blockIdx.x * 8 + r;
    int d = deg[node];
    float di = rsqrtf((float)d + 1.0f);
    if (c == 0) { dinv[node] = di; degi[r] = d; }
    size_t a = (size_t)node * EMB + c;
    xwh[a] = __float2half(__half2float(xwh[a]) * di);
    __syncthreads();
    if (threadIdx.x == 0) {
        int s = 0;
#pragma unroll
        for (int i = 0; i < 8; ++i) s += degi[i];
        atomicAdd(&chist[blockIdx.x >> 3], s);
    }
}

// ---------------------------------------------------------------------------
// Aux (2 blocks x 512): block 0 = exclusive scan of chist[2048] -> cbase
// (2049 entries) + gcursor; block 1 = zero sums + counts via binary search.
// ---------------------------------------------------------------------------
__global__ __launch_bounds__(512) void k_aux(const int* __restrict__ chist,
                                             int* __restrict__ cbase,
                                             int* __restrict__ gcursor,
                                             const int* __restrict__ batch,
                                             float* __restrict__ sums,
                                             float* __restrict__ counts) {
    int t = threadIdx.x;
    if (blockIdx.x == 0) {
        __shared__ int ts[512];
        int v0 = chist[4 * t], v1 = chist[4 * t + 1];
        int v2 = chist[4 * t + 2], v3 = chist[4 * t + 3];
        int s01 = v0 + v1, s012 = s01 + v2, tot = s012 + v3;
        ts[t] = tot;
        __syncthreads();
        for (int off = 1; off < 512; off <<= 1) {
            int u = (t >= off) ? ts[t - off] : 0;
            __syncthreads();
            ts[t] += u;
            __syncthreads();
        }
        int base = ts[t] - tot;   // exclusive over thread chunks
        cbase[4 * t] = base;           gcursor[4 * t] = base;
        cbase[4 * t + 1] = base + v0;  gcursor[4 * t + 1] = base + v0;
        cbase[4 * t + 2] = base + s01; gcursor[4 * t + 2] = base + s01;
        cbase[4 * t + 3] = base + s012; gcursor[4 * t + 3] = base + s012;
        if (t == 511) cbase[2048] = ts[511];
    } else {
        for (int i = t; i < NUM_GRAPHS * EMB; i += 512) sums[i] = 0.f;
        if (t < NUM_GRAPHS) {
            int lo = 0, hi = N_NODES;
            while (lo < hi) { int mid = (lo + hi) >> 1; if (batch[mid] < t) lo = mid + 1; else hi = mid; }
            int a = lo;
            lo = 0; hi = N_NODES;
            int g1 = t + 1;
            while (lo < hi) { int mid = (lo + hi) >> 1; if (batch[mid] < g1) lo = mid + 1; else hi = mid; }
            counts[t] = (float)(lo - a);
        }
    }
}

// ---------------------------------------------------------------------------
// Fill: group edges by 64-node bucket (dst>>6), direct global placement.
// rec = (dst&63)<<24 | src.  Bases reserved before writes -> runs ~4 recs.
// ---------------------------------------------------------------------------
__global__ __launch_bounds__(512) void k_fill1(const int* __restrict__ ei,
                                               int* __restrict__ gcursor,
                                               unsigned int* __restrict__ recs) {
    __shared__ int hist[NBP];
    __shared__ int gbase[NBP];
    __shared__ int lcur[NBP];
    int t = threadIdx.x;
    for (int i = t; i < NBP; i += 512) { hist[i] = 0; lcur[i] = 0; }
    __syncthreads();
    int e0 = blockIdx.x * F1_EPB;
    int s[16], d[16];
#pragma unroll
    for (int k = 0; k < 16; ++k) {
        int e = e0 + k * 512 + t;
        if (e < N_EDGES) {
            s[k] = ei[e];
            d[k] = ei[N_EDGES + e];
            atomicAdd(&hist[d[k] >> 6], 1);
        } else {
            d[k] = -1;
        }
    }
    __syncthreads();
    for (int i = t; i < NBP; i += 512)
        if (hist[i]) gbase[i] = atomicAdd(&gcursor[i], hist[i]);
    __syncthreads();
#pragma unroll
    for (int k = 0; k < 16; ++k) {
        if (d[k] >= 0) {
            int b = d[k] >> 6;
            int pos = gbase[b] + atomicAdd(&lcur[b], 1);
            recs[pos] = ((unsigned int)(d[k] & 63) << 24) | (unsigned int)s[k];
        }
    }
}

// ---------------------------------------------------------------------------
// Bucket gather: one block per 64-node bucket (1563 blocks, 6/CU).
// 16 groups of 32 lanes stream the bucket's records: broadcast rec load,
// random 64B xws row load, ds_add_f32 into acc[64][32] (bank==lane, 2-way
// aliasing = free). Fused epilogue: self-loop + tanh + sorted-batch pool.
// ---------------------------------------------------------------------------
__global__ __launch_bounds__(512) void k_bg(const unsigned int* __restrict__ recs,
                                            const int* __restrict__ cbase,
                                            const __half* __restrict__ xws,
                                            const float* __restrict__ dinv,
                                            const int* __restrict__ batch,
                                            const float* __restrict__ b1,
                                            float* __restrict__ sums) {
    __shared__ float acc[64 * EMB];   // 8 KB
    int t = threadIdx.x, b = blockIdx.x;
    for (int i = t; i < 64 * EMB; i += 512) acc[i] = 0.f;
    __syncthreads();
    int seg1 = cbase[b + 1];
    int g = t >> 5, c = t & 31;
    int j = cbase[b] + g;
    for (; j + 48 < seg1; j += 64) {
        unsigned int r0 = recs[j],      r1 = recs[j + 16];
        unsigned int r2 = recs[j + 32], r3 = recs[j + 48];
        float v0 = __half2float(xws[(r0 & 0xFFFFFF) * EMB + c]);
        float v1 = __half2float(xws[(r1 & 0xFFFFFF) * EMB + c]);
        float v2 = __half2float(xws[(r2 & 0xFFFFFF) * EMB + c]);
        float v3 = __half2float(xws[(r3 & 0xFFFFFF) * EMB + c]);
        atomicAdd(&acc[(r0 >> 24) * EMB + c], v0);
        atomicAdd(&acc[(r1 >> 24) * EMB + c], v1);
        atomicAdd(&acc[(r2 >> 24) * EMB + c], v2);
        atomicAdd(&acc[(r3 >> 24) * EMB + c], v3);
    }
    for (; j < seg1; j += 16) {
        unsigned int r = recs[j];
        atomicAdd(&acc[(r >> 24) * EMB + c],
                  __half2float(xws[(r & 0xFFFFFF) * EMB + c]));
    }
    __syncthreads();
    int node0 = b << 6;
    // self-loop + tanh in place: h = tanh((acc + xws[i]) * dinv[i] + b1)
    for (int rr = t >> 5; rr < 64; rr += 16) {
        int node = node0 + rr;
        if (node < N_NODES) {
            float di = dinv[node];
            float h = tanhf((acc[rr * EMB + c] + __half2float(xws[(size_t)node * EMB + c])) * di + b1[c]);
            acc[rr * EMB + c] = h;
        }
    }
    __syncthreads();
    // pool: waves 0,1 (lanes 0-31) reduce rows 0-31 / 32-63, merging batch runs
    int w = t >> 6, lane = t & 63;
    if (w < 2 && lane < 32) {
        int cc = lane, r0 = w * 32, rr = r0;
        while (rr < r0 + 32) {
            int node = node0 + rr;
            if (node >= N_NODES) break;
            int g0 = batch[node];
            float a = acc[rr * EMB + cc];
            int r2 = rr + 1;
            while (r2 < r0 + 32 && node0 + r2 < N_NODES && batch[node0 + r2] == g0) {
                a += acc[r2 * EMB + cc];
                ++r2;
            }
            atomicAdd(&sums[g0 * EMB + cc], a);
            rr = r2;
        }
    }
}

// ---------------------------------------------------------------------------
// head: out[g] = [sums, means] @ Wout + bout
// ---------------------------------------------------------------------------
__global__ __launch_bounds__(64) void k_out(const float* __restrict__ sums,
                                            const float* __restrict__ counts,
                                            const float* __restrict__ Wout,
                                            const float* __restrict__ bout,
                                            float* __restrict__ out) {
    int g = blockIdx.x * 64 + threadIdx.x;
    if (g >= NUM_GRAPHS) return;
    float inv = 1.0f / fmaxf(counts[g], 1.0f);
    float acc = bout[0];
#pragma unroll
    for (int c = 0; c < EMB; ++c) {
        float s = sums[g * EMB + c];
        acc += s * Wout[c] + s * inv * Wout[EMB + c];
    }
    out[g] = acc;
}

extern "C" void kernel_launch(void* const* d_in, const int* in_sizes, int n_in,
                              void* d_out, int out_size, void* d_ws, size_t ws_size,
                              hipStream_t stream) {
    const float* x     = (const float*)d_in[0];
    const int*   ei    = (const int*)d_in[1];   // [2, E]
    const int*   batch = (const int*)d_in[2];   // [N], sorted
    const float* W1    = (const float*)d_in[3];
    const float* b1    = (const float*)d_in[4];
    const float* Wout  = (const float*)d_in[5];
    const float* bout  = (const float*)d_in[6];
    float* out = (float*)d_out;

    // workspace (~20 MB)
    char* ws = (char*)d_ws;
    __half* xwh        = (__half*)ws;       ws += (size_t)N_NODES * EMB * sizeof(__half);  // 6.4 MB
    unsigned int* recs = (unsigned int*)ws; ws += (size_t)N_EDGES * sizeof(int);           // 12.8 MB
    int*   deg         = (int*)ws;          ws += (size_t)N_NODES * sizeof(int);           // 0.4 MB
    float* dinv        = (float*)ws;        ws += (size_t)N_NODES * sizeof(float);         // 0.4 MB
    int*   chist       = (int*)ws;          ws += NBP * sizeof(int);
    int*   cbase       = (int*)ws;          ws += (NBP + 2) * sizeof(int);
    int*   gcursor     = (int*)ws;          ws += NBP * sizeof(int);
    float* sums        = (float*)ws;        ws += (size_t)NUM_GRAPHS * EMB * sizeof(float);
    float* counts      = (float*)ws;

    hipMemsetAsync(deg, 0, (size_t)N_NODES * sizeof(int), stream);

    k_xw   <<<XW_BLOCKS, 256, 0, stream>>>(x, W1, ei, xwh, deg, chist);
    k_scale<<<N_NODES / 8, 256, 0, stream>>>(deg, xwh, dinv, chist);
    k_aux  <<<2, 512, 0, stream>>>(chist, cbase, gcursor, batch, sums, counts);
    k_fill1<<<F1_BLOCKS, 512, 0, stream>>>(ei, gcursor, recs);
    k_bg   <<<NB, 512, 0, stream>>>(recs, cbase, xwh, dinv, batch, b1, sums);
    k_out  <<<(NUM_GRAPHS + 63) / 64, 64, 0, stream>>>(sums, counts, Wout, bout, out);
}

// Round 7
// 419.745 us; speedup vs baseline: 2.1230x; 2.1230x over previous
//
#include <hip/hip_runtime.h>
#include <hip/hip_fp16.h>

#define N_NODES    100000
#define N_EDGES    3200000
#define IN_DIM     128
#define EMB        32
#define NUM_GRAPHS 256

#define FB         512       // coarse buckets (391 used: bucket = dst >> 8)
#define F1_EPB     8192      // edges per fill block
#define F1_BLOCKS  391       // ceil(N_EDGES / F1_EPB)
#define NBUCKETS   391       // ceil(N_NODES / 256)
#define XW_BLOCKS  1563      // ceil(N_NODES / 64); 1563*2048 >= N_EDGES
#define XW_EPB     2048      // edges deg-counted per xw block

typedef _Float16 half8 __attribute__((ext_vector_type(8)));
typedef float floatx4 __attribute__((ext_vector_type(4)));

// ---------------------------------------------------------------------------
// Kernel 1: xw = x @ W1 -> fp16 via MFMA 16x16x32_f16 (one wave = 16 rows).
// Also folds the exact in-degree count (3.2M global atomics, hidden behind
// the 51 MB x stream).  deg must be zeroed before this kernel.
// ---------------------------------------------------------------------------
__global__ __launch_bounds__(256) void k_xw(const float* __restrict__ x,
                                            const float* __restrict__ W1,
                                            const int* __restrict__ ei,
                                            __half* __restrict__ xwh,
                                            int* __restrict__ deg) {
    {   // degree slice: edges [blockIdx*XW_EPB, +XW_EPB)
        int e0 = blockIdx.x * XW_EPB;
        for (int k = threadIdx.x; k < XW_EPB; k += 256) {
            int e = e0 + k;
            if (e < N_EDGES) atomicAdd(&deg[ei[N_EDGES + e]], 1);
        }
    }
    __shared__ _Float16 Wh[IN_DIM * EMB];   // 8 KB
    for (int i = threadIdx.x; i < IN_DIM * EMB; i += 256)
        Wh[i] = (_Float16)W1[i];
    __syncthreads();
    int wave = threadIdx.x >> 6;
    int lane = threadIdx.x & 63;
    int m = lane & 15, quad = lane >> 4;
    int row0 = (blockIdx.x * 4 + wave) * 16;
    if (row0 >= N_NODES) return;
    half8 bfrag[2][4];
#pragma unroll
    for (int nt = 0; nt < 2; ++nt)
#pragma unroll
        for (int ks = 0; ks < 4; ++ks)
#pragma unroll
            for (int j = 0; j < 8; ++j)
                bfrag[nt][ks][j] = Wh[(ks * 32 + quad * 8 + j) * EMB + nt * 16 + m];
    const float* xr = x + (size_t)(row0 + m) * IN_DIM + quad * 8;
    floatx4 c0 = {0.f, 0.f, 0.f, 0.f}, c1 = {0.f, 0.f, 0.f, 0.f};
#pragma unroll
    for (int ks = 0; ks < 4; ++ks) {
        float4 a0 = *(const float4*)(xr + ks * 32);
        float4 a1 = *(const float4*)(xr + ks * 32 + 4);
        half8 af;
        af[0] = (_Float16)a0.x; af[1] = (_Float16)a0.y;
        af[2] = (_Float16)a0.z; af[3] = (_Float16)a0.w;
        af[4] = (_Float16)a1.x; af[5] = (_Float16)a1.y;
        af[6] = (_Float16)a1.z; af[7] = (_Float16)a1.w;
        c0 = __builtin_amdgcn_mfma_f32_16x16x32_f16(af, bfrag[0][ks], c0, 0, 0, 0);
        c1 = __builtin_amdgcn_mfma_f32_16x16x32_f16(af, bfrag[1][ks], c1, 0, 0, 0);
    }
#pragma unroll
    for (int r = 0; r < 4; ++r) {
        int ro = row0 + quad * 4 + r;
        xwh[(size_t)ro * EMB + m]      = __float2half(c0[r]);
        xwh[(size_t)ro * EMB + 16 + m] = __float2half(c1[r]);
    }
}

// ---------------------------------------------------------------------------
// Aux (2 blocks x 512): block 0 = chist from deg (LDS) -> exclusive scan ->
// cbase[513] + gcursor; block 1 = zero sums + per-graph counts (binary search).
// ---------------------------------------------------------------------------
__global__ __launch_bounds__(512) void k_aux(const int* __restrict__ deg,
                                             int* __restrict__ cbase,
                                             int* __restrict__ gcursor,
                                             const int* __restrict__ batch,
                                             float* __restrict__ sums,
                                             float* __restrict__ counts) {
    int t = threadIdx.x;
    if (blockIdx.x == 0) {
        __shared__ int chl[FB];
        __shared__ int sc[FB];
        chl[t] = 0;
        __syncthreads();
        for (int i = t; i < N_NODES; i += 512)
            atomicAdd(&chl[i >> 8], deg[i]);
        __syncthreads();
        int v = chl[t];
        sc[t] = v;
        __syncthreads();
        for (int off = 1; off < FB; off <<= 1) {
            int u = (t >= off) ? sc[t - off] : 0;
            __syncthreads();
            sc[t] += u;
            __syncthreads();
        }
        int excl = sc[t] - v;
        cbase[t] = excl;
        gcursor[t] = excl;
        if (t == FB - 1) cbase[FB] = sc[FB - 1];
    } else {
        for (int i = t; i < NUM_GRAPHS * EMB; i += 512) sums[i] = 0.f;
        if (t < NUM_GRAPHS) {
            int lo = 0, hi = N_NODES;
            while (lo < hi) { int mid = (lo + hi) >> 1; if (batch[mid] < t) lo = mid + 1; else hi = mid; }
            int a = lo;
            lo = 0; hi = N_NODES;
            int g1 = t + 1;
            while (lo < hi) { int mid = (lo + hi) >> 1; if (batch[mid] < g1) lo = mid + 1; else hi = mid; }
            counts[t] = (float)(lo - a);
        }
    }
}

// ---------------------------------------------------------------------------
// Fill: group edges by coarse bucket (dst>>8), direct global placement
// (bases reserved before writes -> ~84 B runs, writeback ~ payload).
// rec = (dst&255)<<24 | src
// ---------------------------------------------------------------------------
__global__ __launch_bounds__(512) void k_fill1(const int* __restrict__ ei,
                                               int* __restrict__ gcursor,
                                               unsigned int* __restrict__ recs) {
    __shared__ int hist[FB];
    __shared__ int base[FB];
    __shared__ int lcur[FB];
    int t = threadIdx.x;
    hist[t] = 0;
    lcur[t] = 0;
    __syncthreads();
    int e0 = blockIdx.x * F1_EPB;
    int s[16], d[16];
#pragma unroll
    for (int k = 0; k < 16; ++k) {
        int e = e0 + k * 512 + t;
        if (e < N_EDGES) {
            s[k] = ei[e];
            d[k] = ei[N_EDGES + e];
            atomicAdd(&hist[d[k] >> 8], 1);
        } else {
            d[k] = -1;
        }
    }
    __syncthreads();
    if (hist[t]) base[t] = atomicAdd(&gcursor[t], hist[t]);
    __syncthreads();
#pragma unroll
    for (int k = 0; k < 16; ++k) {
        if (d[k] >= 0) {
            int b = d[k] >> 8;
            int pos = base[b] + atomicAdd(&lcur[b], 1);
            recs[pos] = ((unsigned int)(d[k] & 255) << 24) | (unsigned int)s[k];
        }
    }
}

// ---------------------------------------------------------------------------
// Fill2: one block per bucket. Per-node offsets come from deg (NO histogram
// pass, NO staging): scan deg slice -> rowstart + dinv + cursors, then stream
// recs once, placing via LDS cursor atomics (scatter stays in a 33 KB L2-local
// window). Finally scales xwh rows in place by dinv.
// ---------------------------------------------------------------------------
__global__ __launch_bounds__(512) void k_fill2(const unsigned int* __restrict__ recs,
                                               const int* __restrict__ cbase,
                                               const int* __restrict__ deg,
                                               int* __restrict__ edge_src,
                                               int* __restrict__ rowstart,
                                               float* __restrict__ dinv,
                                               __half* __restrict__ xwh) {
    __shared__ int cur2[256], sc[256];
    __shared__ float dv[256];
    int t = threadIdx.x, b = blockIdx.x;
    int seg0 = cbase[b];
    int cnt = cbase[b + 1] - seg0;
    int node0 = b << 8;
    int v = 0;
    if (t < 256) {
        int node = node0 + t;
        v = (node < N_NODES) ? deg[node] : 0;
        sc[t] = v;
    }
    __syncthreads();
    for (int off = 1; off < 256; off <<= 1) {
        int u = 0;
        if (t < 256 && t >= off) u = sc[t - off];
        __syncthreads();
        if (t < 256) sc[t] += u;
        __syncthreads();
    }
    if (t < 256) {
        int excl = sc[t] - v;
        cur2[t] = excl;
        float dval = rsqrtf((float)v + 1.0f);
        dv[t] = dval;
        int node = node0 + t;
        if (node < N_NODES) {
            rowstart[node] = seg0 + excl;
            dinv[node] = dval;
        }
    }
    if (b == 0 && t == 0) rowstart[N_NODES] = N_EDGES;
    __syncthreads();
    for (int j = t; j < cnt; j += 512) {
        unsigned int r = recs[seg0 + j];
        int p = atomicAdd(&cur2[r >> 24], 1);
        edge_src[seg0 + p] = (int)(r & 0x00FFFFFF);
    }
    // scale xwh rows of this bucket in place: xwh[i] *= dinv[i]
    for (int idx = t; idx < 256 * EMB; idx += 512) {
        int node = node0 + (idx >> 5);
        if (node < N_NODES) {
            size_t a = (size_t)node * EMB + (idx & 31);
            xwh[a] = __float2half(__half2float(xwh[a]) * dv[idx >> 5]);
        }
    }
}

// ---------------------------------------------------------------------------
// Fused gather, half2 edition: 16 lanes per node, each lane covers 2 cols via
// __half2 loads -> each wave holds 4 independent rows (2x the loads in flight
// per load-instruction vs 32-lane groups). 6250 blocks x 16 nodes = N_NODES.
// Epilogue: self-loop + tanh + sorted-batch pool.
// ---------------------------------------------------------------------------
__global__ __launch_bounds__(256) void k_gather(const __half* __restrict__ xws,
                                                const float* __restrict__ dinv,
                                                const int* __restrict__ rowstart,
                                                const int* __restrict__ edge_src,
                                                const int* __restrict__ batch,
                                                const float* __restrict__ b1,
                                                float* __restrict__ sums) {
    const __half2* rows = (const __half2*)xws;   // row stride = 16 half2
    int grp = threadIdx.x >> 4;          // node slot 0..15
    int cc  = threadIdx.x & 15;          // half2 column
    int i = blockIdx.x * 16 + grp;
    float di = dinv[i];
    int e0 = rowstart[i], e1 = rowstart[i + 1];
    float a0 = 0.f, a1 = 0.f;
    int e = e0;
    for (; e + 7 < e1; e += 8) {
        int s0 = edge_src[e],     s1 = edge_src[e + 1];
        int s2 = edge_src[e + 2], s3 = edge_src[e + 3];
        int s4 = edge_src[e + 4], s5 = edge_src[e + 5];
        int s6 = edge_src[e + 6], s7 = edge_src[e + 7];
        float2 f0 = __half22float2(rows[s0 * 16 + cc]);
        float2 f1 = __half22float2(rows[s1 * 16 + cc]);
        float2 f2 = __half22float2(rows[s2 * 16 + cc]);
        float2 f3 = __half22float2(rows[s3 * 16 + cc]);
        float2 f4 = __half22float2(rows[s4 * 16 + cc]);
        float2 f5 = __half22float2(rows[s5 * 16 + cc]);
        float2 f6 = __half22float2(rows[s6 * 16 + cc]);
        float2 f7 = __half22float2(rows[s7 * 16 + cc]);
        a0 += ((f0.x + f1.x) + (f2.x + f3.x)) + ((f4.x + f5.x) + (f6.x + f7.x));
        a1 += ((f0.y + f1.y) + (f2.y + f3.y)) + ((f4.y + f5.y) + (f6.y + f7.y));
    }
    for (; e < e1; ++e) {
        float2 f = __half22float2(rows[edge_src[e] * 16 + cc]);
        a0 += f.x;
        a1 += f.y;
    }
    float2 fs = __half22float2(rows[i * 16 + cc]);
    float2 bb = *(const float2*)(b1 + 2 * cc);
    float h0 = tanhf((a0 + fs.x) * di + bb.x);
    float h1 = tanhf((a1 + fs.y) * di + bb.y);

    __shared__ float hs[16][EMB];
    __shared__ int gb[16];
    *(float2*)&hs[grp][2 * cc] = make_float2(h0, h1);
    if (cc == 0) gb[grp] = batch[i];
    __syncthreads();
    if (threadIdx.x < 32) {
        int col = threadIdx.x;
        int rr = 0;
        while (rr < 16) {
            int g0 = gb[rr];
            float a = hs[rr][col];
            int r2 = rr + 1;
            while (r2 < 16 && gb[r2] == g0) { a += hs[r2][col]; ++r2; }
            atomicAdd(&sums[g0 * EMB + col], a);
            rr = r2;
        }
    }
}

// ---------------------------------------------------------------------------
// head: out[g] = [sums, means] @ Wout + bout
// ---------------------------------------------------------------------------
__global__ __launch_bounds__(64) void k_out(const float* __restrict__ sums,
                                            const float* __restrict__ counts,
                                            const float* __restrict__ Wout,
                                            const float* __restrict__ bout,
                                            float* __restrict__ out) {
    int g = blockIdx.x * 64 + threadIdx.x;
    if (g >= NUM_GRAPHS) return;
    float inv = 1.0f / fmaxf(counts[g], 1.0f);
    float acc = bout[0];
#pragma unroll
    for (int c = 0; c < EMB; ++c) {
        float s = sums[g * EMB + c];
        acc += s * Wout[c] + s * inv * Wout[EMB + c];
    }
    out[g] = acc;
}

extern "C" void kernel_launch(void* const* d_in, const int* in_sizes, int n_in,
                              void* d_out, int out_size, void* d_ws, size_t ws_size,
                              hipStream_t stream) {
    const float* x     = (const float*)d_in[0];
    const int*   ei    = (const int*)d_in[1];   // [2, E]
    const int*   batch = (const int*)d_in[2];   // [N], sorted
    const float* W1    = (const float*)d_in[3];
    const float* b1    = (const float*)d_in[4];
    const float* Wout  = (const float*)d_in[5];
    const float* bout  = (const float*)d_in[6];
    float* out = (float*)d_out;

    // workspace (~33 MB)
    char* ws = (char*)d_ws;
    __half* xwh        = (__half*)ws;       ws += (size_t)N_NODES * EMB * sizeof(__half);  // 6.4 MB
    unsigned int* recs = (unsigned int*)ws; ws += (size_t)N_EDGES * sizeof(int);           // 12.8 MB
    int*   edge_src    = (int*)ws;          ws += (size_t)N_EDGES * sizeof(int);           // 12.8 MB
    int*   deg         = (int*)ws;          ws += (size_t)N_NODES * sizeof(int);           // 0.4 MB
    int*   rowstart    = (int*)ws;          ws += (size_t)(N_NODES + 4) * sizeof(int);     // 0.4 MB
    float* dinv        = (float*)ws;        ws += (size_t)N_NODES * sizeof(float);         // 0.4 MB
    int*   cbase       = (int*)ws;          ws += (FB + 2) * sizeof(int);
    int*   gcursor     = (int*)ws;          ws += FB * sizeof(int);
    float* sums        = (float*)ws;        ws += (size_t)NUM_GRAPHS * EMB * sizeof(float);
    float* counts      = (float*)ws;

    hipMemsetAsync(deg, 0, (size_t)N_NODES * sizeof(int), stream);

    k_xw    <<<XW_BLOCKS, 256, 0, stream>>>(x, W1, ei, xwh, deg);
    k_aux   <<<2, 512, 0, stream>>>(deg, cbase, gcursor, batch, sums, counts);
    k_fill1 <<<F1_BLOCKS, 512, 0, stream>>>(ei, gcursor, recs);
    k_fill2 <<<NBUCKETS, 512, 0, stream>>>(recs, cbase, deg, edge_src, rowstart, dinv, xwh);
    k_gather<<<N_NODES / 16, 256, 0, stream>>>(xwh, dinv, rowstart, edge_src, batch, b1, sums);
    k_out   <<<(NUM_GRAPHS + 63) / 64, 64, 0, stream>>>(sums, counts, Wout, bout, out);
}

// Round 8
// 265.566 us; speedup vs baseline: 3.3555x; 1.5806x over previous
//
#include <hip/hip_runtime.h>
#include <hip/hip_fp16.h>

#define N_NODES    100000
#define N_EDGES    3200000
#define IN_DIM     128
#define EMB        32
#define NUM_GRAPHS 256

#define FB         512       // coarse buckets (391 used: bucket = dst >> 8)
#define F1_EPB     8192      // edges per fill block
#define F1_BLOCKS  391       // ceil(N_EDGES / F1_EPB)
#define NBUCKETS   391       // ceil(N_NODES / 256)
#define XW_BLOCKS  1563      // ceil(N_NODES / 64); 1563*2048 >= N_EDGES
#define XW_EPB     2048      // edges histogrammed per xw block
#define CAP        10240     // fill2 LDS staging (mean 8192, +22 sigma)

typedef _Float16 half8 __attribute__((ext_vector_type(8)));
typedef float floatx4 __attribute__((ext_vector_type(4)));

// ---------------------------------------------------------------------------
// Kernel 1: xw = x @ W1 -> fp16 via MFMA 16x16x32_f16 (one wave = 16 rows).
// Also folds the coarse dst>>8 histogram as LDS hist + <=512 global merge
// atomics per block (NOT per-edge global atomics — R7 lesson: those write
// through to HBM at ~32B each and dominate).  chist pre-zeroed by memset.
// ---------------------------------------------------------------------------
__global__ __launch_bounds__(256) void k_xw(const float* __restrict__ x,
                                            const float* __restrict__ W1,
                                            const int* __restrict__ ei,
                                            __half* __restrict__ xwh,
                                            int* __restrict__ chist) {
    __shared__ _Float16 Wh[IN_DIM * EMB];   // 8 KB
    __shared__ int h[FB];                   // 2 KB
    for (int i = threadIdx.x; i < FB; i += 256) h[i] = 0;
    for (int i = threadIdx.x; i < IN_DIM * EMB; i += 256)
        Wh[i] = (_Float16)W1[i];
    __syncthreads();
    {   // coarse histogram of this block's edge slice (LDS atomics)
        int e0 = blockIdx.x * XW_EPB;
        for (int k = threadIdx.x; k < XW_EPB; k += 256) {
            int e = e0 + k;
            if (e < N_EDGES) atomicAdd(&h[ei[N_EDGES + e] >> 8], 1);
        }
    }
    int wave = threadIdx.x >> 6;
    int lane = threadIdx.x & 63;
    int m = lane & 15, quad = lane >> 4;
    int row0 = (blockIdx.x * 4 + wave) * 16;
    if (row0 < N_NODES) {
        half8 bfrag[2][4];
#pragma unroll
        for (int nt = 0; nt < 2; ++nt)
#pragma unroll
            for (int ks = 0; ks < 4; ++ks)
#pragma unroll
                for (int j = 0; j < 8; ++j)
                    bfrag[nt][ks][j] = Wh[(ks * 32 + quad * 8 + j) * EMB + nt * 16 + m];
        const float* xr = x + (size_t)(row0 + m) * IN_DIM + quad * 8;
        floatx4 c0 = {0.f, 0.f, 0.f, 0.f}, c1 = {0.f, 0.f, 0.f, 0.f};
#pragma unroll
        for (int ks = 0; ks < 4; ++ks) {
            float4 a0 = *(const float4*)(xr + ks * 32);
            float4 a1 = *(const float4*)(xr + ks * 32 + 4);
            half8 af;
            af[0] = (_Float16)a0.x; af[1] = (_Float16)a0.y;
            af[2] = (_Float16)a0.z; af[3] = (_Float16)a0.w;
            af[4] = (_Float16)a1.x; af[5] = (_Float16)a1.y;
            af[6] = (_Float16)a1.z; af[7] = (_Float16)a1.w;
            c0 = __builtin_amdgcn_mfma_f32_16x16x32_f16(af, bfrag[0][ks], c0, 0, 0, 0);
            c1 = __builtin_amdgcn_mfma_f32_16x16x32_f16(af, bfrag[1][ks], c1, 0, 0, 0);
        }
#pragma unroll
        for (int r = 0; r < 4; ++r) {
            int ro = row0 + quad * 4 + r;
            xwh[(size_t)ro * EMB + m]      = __float2half(c0[r]);
            xwh[(size_t)ro * EMB + 16 + m] = __float2half(c1[r]);
        }
    }
    __syncthreads();
    for (int i = threadIdx.x; i < FB; i += 256)
        if (h[i]) atomicAdd(&chist[i], h[i]);
}

// ---------------------------------------------------------------------------
// Aux (2 blocks x 512): block 0 = exclusive scan of chist -> cbase[513] +
// gcursor; block 1 = zero sums + per-graph counts via binary search.
// ---------------------------------------------------------------------------
__global__ __launch_bounds__(512) void k_aux(const int* __restrict__ chist,
                                             int* __restrict__ cbase,
                                             int* __restrict__ gcursor,
                                             const int* __restrict__ batch,
                                             float* __restrict__ sums,
                                             float* __restrict__ counts) {
    int t = threadIdx.x;
    if (blockIdx.x == 0) {
        __shared__ int sc[FB];
        int v = chist[t];
        sc[t] = v;
        __syncthreads();
        for (int off = 1; off < FB; off <<= 1) {
            int u = (t >= off) ? sc[t - off] : 0;
            __syncthreads();
            sc[t] += u;
            __syncthreads();
        }
        int excl = sc[t] - v;
        cbase[t] = excl;
        gcursor[t] = excl;
        if (t == FB - 1) cbase[FB] = sc[FB - 1];
    } else {
        for (int i = t; i < NUM_GRAPHS * EMB; i += 512) sums[i] = 0.f;
        if (t < NUM_GRAPHS) {
            int lo = 0, hi = N_NODES;
            while (lo < hi) { int mid = (lo + hi) >> 1; if (batch[mid] < t) lo = mid + 1; else hi = mid; }
            int a = lo;
            lo = 0; hi = N_NODES;
            int g1 = t + 1;
            while (lo < hi) { int mid = (lo + hi) >> 1; if (batch[mid] < g1) lo = mid + 1; else hi = mid; }
            counts[t] = (float)(lo - a);
        }
    }
}

// ---------------------------------------------------------------------------
// Fill: group edges by coarse bucket (dst>>8), direct global placement
// (bases reserved before writes -> ~84 B runs, writeback ~ payload).
// rec = (dst&255)<<24 | src
// ---------------------------------------------------------------------------
__global__ __launch_bounds__(512) void k_fill1(const int* __restrict__ ei,
                                               int* __restrict__ gcursor,
                                               unsigned int* __restrict__ recs) {
    __shared__ int hist[FB];
    __shared__ int base[FB];
    __shared__ int lcur[FB];
    int t = threadIdx.x;
    hist[t] = 0;
    lcur[t] = 0;
    __syncthreads();
    int e0 = blockIdx.x * F1_EPB;
    int s[16], d[16];
#pragma unroll
    for (int k = 0; k < 16; ++k) {
        int e = e0 + k * 512 + t;
        if (e < N_EDGES) {
            s[k] = ei[e];
            d[k] = ei[N_EDGES + e];
            atomicAdd(&hist[d[k] >> 8], 1);
        } else {
            d[k] = -1;
        }
    }
    __syncthreads();
    if (hist[t]) base[t] = atomicAdd(&gcursor[t], hist[t]);
    __syncthreads();
#pragma unroll
    for (int k = 0; k < 16; ++k) {
        if (d[k] >= 0) {
            int b = d[k] >> 8;
            int pos = base[b] + atomicAdd(&lcur[b], 1);
            recs[pos] = ((unsigned int)(d[k] & 255) << 24) | (unsigned int)s[k];
        }
    }
}

// ---------------------------------------------------------------------------
// Fill2: one block per bucket. LDS histogram of the bucket's recs -> per-node
// offsets (deg) -> rowstart + dinv + cursors; records staged in LDS; exact
// counting sort emits edge_src; then scales xwh rows in place by dinv.
// ---------------------------------------------------------------------------
__global__ __launch_bounds__(512) void k_fill2(const unsigned int* __restrict__ recs,
                                               const int* __restrict__ cbase,
                                               int* __restrict__ edge_src,
                                               int* __restrict__ rowstart,
                                               float* __restrict__ dinv,
                                               __half* __restrict__ xwh) {
    __shared__ unsigned int lbuf[CAP];          // 40 KB
    __shared__ int h2[256], cur2[256], sc[256];
    __shared__ float dv[256];
    int t = threadIdx.x, b = blockIdx.x;
    if (t < 256) h2[t] = 0;
    __syncthreads();
    int seg0 = cbase[b];
    int cnt = cbase[b + 1] - seg0;
    for (int j = t; j < cnt; j += 512) {
        unsigned int r = recs[seg0 + j];
        if (j < CAP) lbuf[j] = r;
        atomicAdd(&h2[r >> 24], 1);
    }
    __syncthreads();
    int v = 0;
    if (t < 256) { v = h2[t]; sc[t] = v; }
    __syncthreads();
    for (int off = 1; off < 256; off <<= 1) {
        int u = 0;
        if (t < 256 && t >= off) u = sc[t - off];
        __syncthreads();
        if (t < 256) sc[t] += u;
        __syncthreads();
    }
    int node0 = b << 8;
    if (t < 256) {
        int excl = sc[t] - v;
        cur2[t] = excl;
        float dval = rsqrtf((float)v + 1.0f);
        dv[t] = dval;
        int node = node0 + t;
        if (node < N_NODES) {
            rowstart[node] = seg0 + excl;
            dinv[node] = dval;
        }
    }
    if (b == 0 && t == 0) rowstart[N_NODES] = N_EDGES;
    __syncthreads();
    for (int j = t; j < cnt; j += 512) {
        unsigned int r = (j < CAP) ? lbuf[j] : recs[seg0 + j];
        int p = atomicAdd(&cur2[r >> 24], 1);
        edge_src[seg0 + p] = (int)(r & 0x00FFFFFF);
    }
    // scale xwh rows of this bucket in place: xwh[i] *= dinv[i]
    for (int idx = t; idx < 256 * EMB; idx += 512) {
        int node = node0 + (idx >> 5);
        if (node < N_NODES) {
            size_t a = (size_t)node * EMB + (idx & 31);
            xwh[a] = __float2half(__half2float(xwh[a]) * dv[idx >> 5]);
        }
    }
}

// ---------------------------------------------------------------------------
// Fused gather, half2: 16 lanes per node, each lane 2 cols -> 4 independent
// rows per wave. 6250 blocks x 16 nodes = N_NODES. Epilogue: self-loop +
// tanh + sorted-batch pool.
// ---------------------------------------------------------------------------
__global__ __launch_bounds__(256) void k_gather(const __half* __restrict__ xws,
                                                const float* __restrict__ dinv,
                                                const int* __restrict__ rowstart,
                                                const int* __restrict__ edge_src,
                                                const int* __restrict__ batch,
                                                const float* __restrict__ b1,
                                                float* __restrict__ sums) {
    const __half2* rows = (const __half2*)xws;   // row stride = 16 half2
    int grp = threadIdx.x >> 4;          // node slot 0..15
    int cc  = threadIdx.x & 15;          // half2 column
    int i = blockIdx.x * 16 + grp;
    float di = dinv[i];
    int e0 = rowstart[i], e1 = rowstart[i + 1];
    float a0 = 0.f, a1 = 0.f;
    int e = e0;
    for (; e + 7 < e1; e += 8) {
        int s0 = edge_src[e],     s1 = edge_src[e + 1];
        int s2 = edge_src[e + 2], s3 = edge_src[e + 3];
        int s4 = edge_src[e + 4], s5 = edge_src[e + 5];
        int s6 = edge_src[e + 6], s7 = edge_src[e + 7];
        float2 f0 = __half22float2(rows[s0 * 16 + cc]);
        float2 f1 = __half22float2(rows[s1 * 16 + cc]);
        float2 f2 = __half22float2(rows[s2 * 16 + cc]);
        float2 f3 = __half22float2(rows[s3 * 16 + cc]);
        float2 f4 = __half22float2(rows[s4 * 16 + cc]);
        float2 f5 = __half22float2(rows[s5 * 16 + cc]);
        float2 f6 = __half22float2(rows[s6 * 16 + cc]);
        float2 f7 = __half22float2(rows[s7 * 16 + cc]);
        a0 += ((f0.x + f1.x) + (f2.x + f3.x)) + ((f4.x + f5.x) + (f6.x + f7.x));
        a1 += ((f0.y + f1.y) + (f2.y + f3.y)) + ((f4.y + f5.y) + (f6.y + f7.y));
    }
    for (; e < e1; ++e) {
        float2 f = __half22float2(rows[edge_src[e] * 16 + cc]);
        a0 += f.x;
        a1 += f.y;
    }
    float2 fs = __half22float2(rows[i * 16 + cc]);
    float2 bb = *(const float2*)(b1 + 2 * cc);
    float h0 = tanhf((a0 + fs.x) * di + bb.x);
    float h1 = tanhf((a1 + fs.y) * di + bb.y);

    __shared__ float hs[16][EMB];
    __shared__ int gb[16];
    *(float2*)&hs[grp][2 * cc] = make_float2(h0, h1);
    if (cc == 0) gb[grp] = batch[i];
    __syncthreads();
    if (threadIdx.x < 32) {
        int col = threadIdx.x;
        int rr = 0;
        while (rr < 16) {
            int g0 = gb[rr];
            float a = hs[rr][col];
            int r2 = rr + 1;
            while (r2 < 16 && gb[r2] == g0) { a += hs[r2][col]; ++r2; }
            atomicAdd(&sums[g0 * EMB + col], a);
            rr = r2;
        }
    }
}

// ---------------------------------------------------------------------------
// head: out[g] = [sums, means] @ Wout + bout
// ---------------------------------------------------------------------------
__global__ __launch_bounds__(64) void k_out(const float* __restrict__ sums,
                                            const float* __restrict__ counts,
                                            const float* __restrict__ Wout,
                                            const float* __restrict__ bout,
                                            float* __restrict__ out) {
    int g = blockIdx.x * 64 + threadIdx.x;
    if (g >= NUM_GRAPHS) return;
    float inv = 1.0f / fmaxf(counts[g], 1.0f);
    float acc = bout[0];
#pragma unroll
    for (int c = 0; c < EMB; ++c) {
        float s = sums[g * EMB + c];
        acc += s * Wout[c] + s * inv * Wout[EMB + c];
    }
    out[g] = acc;
}

extern "C" void kernel_launch(void* const* d_in, const int* in_sizes, int n_in,
                              void* d_out, int out_size, void* d_ws, size_t ws_size,
                              hipStream_t stream) {
    const float* x     = (const float*)d_in[0];
    const int*   ei    = (const int*)d_in[1];   // [2, E]
    const int*   batch = (const int*)d_in[2];   // [N], sorted
    const float* W1    = (const float*)d_in[3];
    const float* b1    = (const float*)d_in[4];
    const float* Wout  = (const float*)d_in[5];
    const float* bout  = (const float*)d_in[6];
    float* out = (float*)d_out;

    // workspace (~33 MB)
    char* ws = (char*)d_ws;
    __half* xwh        = (__half*)ws;       ws += (size_t)N_NODES * EMB * sizeof(__half);  // 6.4 MB
    unsigned int* recs = (unsigned int*)ws; ws += (size_t)N_EDGES * sizeof(int);           // 12.8 MB
    int*   edge_src    = (int*)ws;          ws += (size_t)N_EDGES * sizeof(int);           // 12.8 MB
    int*   rowstart    = (int*)ws;          ws += (size_t)(N_NODES + 4) * sizeof(int);     // 0.4 MB
    float* dinv        = (float*)ws;        ws += (size_t)N_NODES * sizeof(float);         // 0.4 MB
    int*   chist       = (int*)ws;          ws += FB * sizeof(int);
    int*   cbase       = (int*)ws;          ws += (FB + 2) * sizeof(int);
    int*   gcursor     = (int*)ws;          ws += FB * sizeof(int);
    float* sums        = (float*)ws;        ws += (size_t)NUM_GRAPHS * EMB * sizeof(float);
    float* counts      = (float*)ws;

    hipMemsetAsync(chist, 0, FB * sizeof(int), stream);

    k_xw    <<<XW_BLOCKS, 256, 0, stream>>>(x, W1, ei, xwh, chist);
    k_aux   <<<2, 512, 0, stream>>>(chist, cbase, gcursor, batch, sums, counts);
    k_fill1 <<<F1_BLOCKS, 512, 0, stream>>>(ei, gcursor, recs);
    k_fill2 <<<NBUCKETS, 512, 0, stream>>>(recs, cbase, edge_src, rowstart, dinv, xwh);
    k_gather<<<N_NODES / 16, 256, 0, stream>>>(xwh, dinv, rowstart, edge_src, batch, b1, sums);
    k_out   <<<(NUM_GRAPHS + 63) / 64, 64, 0, stream>>>(sums, counts, Wout, bout, out);
}

// Round 9
// 264.647 us; speedup vs baseline: 3.3672x; 1.0035x over previous
//
#include <hip/hip_runtime.h>
#include <hip/hip_fp16.h>

#define N_NODES    100000
#define N_EDGES    3200000
#define IN_DIM     128
#define EMB        32
#define NUM_GRAPHS 256

#define FB         1024      // coarse buckets (782 used: bucket = dst >> 7)
#define NODES_PB   128       // nodes per bucket
#define NBUCKETS   782       // ceil(N_NODES / 128)
#define F1_EPB     8192      // edges per fill block
#define F1_BLOCKS  391       // ceil(N_EDGES / F1_EPB)
#define H_EPB      2048      // edges per hist block
#define H_BLOCKS   1563      // ceil(N_EDGES / H_EPB)
#define XW_BLOCKS  1563      // ceil(N_NODES / 64)
#define CAP        5632      // fill2 LDS staging (mean 4092, +24 sigma)

typedef _Float16 half8 __attribute__((ext_vector_type(8)));
typedef float floatx4 __attribute__((ext_vector_type(4)));

// ---------------------------------------------------------------------------
// Coarse histogram of dst>>7. 1563 blocks (occupancy), LDS hist + <=1024
// global merge atomics per block.  chist pre-zeroed by memset.
// ---------------------------------------------------------------------------
__global__ __launch_bounds__(256) void k_hist1(const int* __restrict__ ei,
                                               int* __restrict__ chist) {
    __shared__ int h[FB];
    for (int i = threadIdx.x; i < FB; i += 256) h[i] = 0;
    __syncthreads();
    int e0 = blockIdx.x * H_EPB;
    for (int k = threadIdx.x; k < H_EPB; k += 256) {
        int e = e0 + k;
        if (e < N_EDGES) atomicAdd(&h[ei[N_EDGES + e] >> 7], 1);
    }
    __syncthreads();
    for (int i = threadIdx.x; i < FB; i += 256)
        if (h[i]) atomicAdd(&chist[i], h[i]);
}

// ---------------------------------------------------------------------------
// Aux (2 blocks x 512): block 0 = exclusive scan of chist[1024] (2 elems per
// thread) -> cbase[1025] + gcursor; block 1 = zero sums + per-graph counts.
// ---------------------------------------------------------------------------
__global__ __launch_bounds__(512) void k_aux(const int* __restrict__ chist,
                                             int* __restrict__ cbase,
                                             int* __restrict__ gcursor,
                                             const int* __restrict__ batch,
                                             float* __restrict__ sums,
                                             float* __restrict__ counts) {
    int t = threadIdx.x;
    if (blockIdx.x == 0) {
        __shared__ int ts[512];
        int v0 = chist[2 * t], v1 = chist[2 * t + 1];
        int tot = v0 + v1;
        ts[t] = tot;
        __syncthreads();
        for (int off = 1; off < 512; off <<= 1) {
            int u = (t >= off) ? ts[t - off] : 0;
            __syncthreads();
            ts[t] += u;
            __syncthreads();
        }
        int base = ts[t] - tot;
        cbase[2 * t] = base;          gcursor[2 * t] = base;
        cbase[2 * t + 1] = base + v0; gcursor[2 * t + 1] = base + v0;
        if (t == 511) cbase[FB] = ts[511];
    } else {
        for (int i = t; i < NUM_GRAPHS * EMB; i += 512) sums[i] = 0.f;
        if (t < NUM_GRAPHS) {
            int lo = 0, hi = N_NODES;
            while (lo < hi) { int mid = (lo + hi) >> 1; if (batch[mid] < t) lo = mid + 1; else hi = mid; }
            int a = lo;
            lo = 0; hi = N_NODES;
            int g1 = t + 1;
            while (lo < hi) { int mid = (lo + hi) >> 1; if (batch[mid] < g1) lo = mid + 1; else hi = mid; }
            counts[t] = (float)(lo - a);
        }
    }
}

// ---------------------------------------------------------------------------
// Fill1: group edges by bucket (dst>>7), direct global placement (bases
// reserved before writes -> contiguous runs, writeback ~ payload).
// rec = (dst&127)<<24 | src
// ---------------------------------------------------------------------------
__global__ __launch_bounds__(512) void k_fill1(const int* __restrict__ ei,
                                               int* __restrict__ gcursor,
                                               unsigned int* __restrict__ recs) {
    __shared__ int hist[FB];
    __shared__ int base[FB];
    __shared__ int lcur[FB];
    int t = threadIdx.x;
    for (int i = t; i < FB; i += 512) { hist[i] = 0; lcur[i] = 0; }
    __syncthreads();
    int e0 = blockIdx.x * F1_EPB;
    int s[16], d[16];
#pragma unroll
    for (int k = 0; k < 16; ++k) {
        int e = e0 + k * 512 + t;
        if (e < N_EDGES) {
            s[k] = ei[e];
            d[k] = ei[N_EDGES + e];
            atomicAdd(&hist[d[k] >> 7], 1);
        } else {
            d[k] = -1;
        }
    }
    __syncthreads();
    for (int i = t; i < FB; i += 512)
        if (hist[i]) base[i] = atomicAdd(&gcursor[i], hist[i]);
    __syncthreads();
#pragma unroll
    for (int k = 0; k < 16; ++k) {
        if (d[k] >= 0) {
            int b = d[k] >> 7;
            int pos = base[b] + atomicAdd(&lcur[b], 1);
            recs[pos] = ((unsigned int)(d[k] & 127) << 24) | (unsigned int)s[k];
        }
    }
}

// ---------------------------------------------------------------------------
// Fill2: one block per 128-node bucket (782 blocks, ~24 KB LDS -> 6/CU).
// LDS histogram of bucket's recs -> deg -> rowstart + dinv + cursors; staged
// counting sort emits edge_src. No xwh access (moved to k_xw).
// ---------------------------------------------------------------------------
__global__ __launch_bounds__(512) void k_fill2(const unsigned int* __restrict__ recs,
                                               const int* __restrict__ cbase,
                                               int* __restrict__ edge_src,
                                               int* __restrict__ rowstart,
                                               float* __restrict__ dinv) {
    __shared__ unsigned int lbuf[CAP];          // 22 KB
    __shared__ int h2[NODES_PB], cur2[NODES_PB], sc[NODES_PB];
    int t = threadIdx.x, b = blockIdx.x;
    if (t < NODES_PB) h2[t] = 0;
    __syncthreads();
    int seg0 = cbase[b];
    int cnt = cbase[b + 1] - seg0;
    for (int j = t; j < cnt; j += 512) {
        unsigned int r = recs[seg0 + j];
        if (j < CAP) lbuf[j] = r;
        atomicAdd(&h2[r >> 24], 1);
    }
    __syncthreads();
    int v = 0;
    if (t < NODES_PB) { v = h2[t]; sc[t] = v; }
    __syncthreads();
    for (int off = 1; off < NODES_PB; off <<= 1) {
        int u = 0;
        if (t < NODES_PB && t >= off) u = sc[t - off];
        __syncthreads();
        if (t < NODES_PB) sc[t] += u;
        __syncthreads();
    }
    int node0 = b << 7;
    if (t < NODES_PB) {
        int excl = sc[t] - v;
        cur2[t] = excl;
        int node = node0 + t;
        if (node < N_NODES) {
            rowstart[node] = seg0 + excl;
            dinv[node] = rsqrtf((float)v + 1.0f);
        }
    }
    if (b == 0 && t == 0) rowstart[N_NODES] = N_EDGES;
    __syncthreads();
    for (int j = t; j < cnt; j += 512) {
        unsigned int r = (j < CAP) ? lbuf[j] : recs[seg0 + j];
        int p = atomicAdd(&cur2[r >> 24], 1);
        edge_src[seg0 + p] = (int)(r & 0x00FFFFFF);
    }
}

// ---------------------------------------------------------------------------
// xw = (x @ W1) * dinv[row] -> fp16 via MFMA 16x16x32_f16 (one wave = 16
// rows). Runs AFTER fill2 so the dinv scale folds in here (saves fill2's
// 12.8 MB xwh round-trip). Wh padded to stride 33 -> bfrag reads conflict-
// free (R8: stride 32 put all 4 quads on one bank, 1.05M conflicts).
// ---------------------------------------------------------------------------
__global__ __launch_bounds__(256) void k_xw(const float* __restrict__ x,
                                            const float* __restrict__ W1,
                                            const float* __restrict__ dinv,
                                            __half* __restrict__ xwh) {
    __shared__ _Float16 Wh[IN_DIM * (EMB + 1)];   // 8.25 KB, padded stride 33
    for (int i = threadIdx.x; i < IN_DIM * EMB; i += 256)
        Wh[(i >> 5) * (EMB + 1) + (i & 31)] = (_Float16)W1[i];
    __syncthreads();
    int wave = threadIdx.x >> 6;
    int lane = threadIdx.x & 63;
    int m = lane & 15, quad = lane >> 4;
    int row0 = (blockIdx.x * 4 + wave) * 16;
    if (row0 >= N_NODES) return;
    half8 bfrag[2][4];
#pragma unroll
    for (int nt = 0; nt < 2; ++nt)
#pragma unroll
        for (int ks = 0; ks < 4; ++ks)
#pragma unroll
            for (int j = 0; j < 8; ++j)
                bfrag[nt][ks][j] = Wh[(ks * 32 + quad * 8 + j) * (EMB + 1) + nt * 16 + m];
    const float* xr = x + (size_t)(row0 + m) * IN_DIM + quad * 8;
    floatx4 c0 = {0.f, 0.f, 0.f, 0.f}, c1 = {0.f, 0.f, 0.f, 0.f};
#pragma unroll
    for (int ks = 0; ks < 4; ++ks) {
        float4 a0 = *(const float4*)(xr + ks * 32);
        float4 a1 = *(const float4*)(xr + ks * 32 + 4);
        half8 af;
        af[0] = (_Float16)a0.x; af[1] = (_Float16)a0.y;
        af[2] = (_Float16)a0.z; af[3] = (_Float16)a0.w;
        af[4] = (_Float16)a1.x; af[5] = (_Float16)a1.y;
        af[6] = (_Float16)a1.z; af[7] = (_Float16)a1.w;
        c0 = __builtin_amdgcn_mfma_f32_16x16x32_f16(af, bfrag[0][ks], c0, 0, 0, 0);
        c1 = __builtin_amdgcn_mfma_f32_16x16x32_f16(af, bfrag[1][ks], c1, 0, 0, 0);
    }
#pragma unroll
    for (int r = 0; r < 4; ++r) {
        int ro = row0 + quad * 4 + r;
        float di = dinv[ro];
        xwh[(size_t)ro * EMB + m]      = __float2half(c0[r] * di);
        xwh[(size_t)ro * EMB + 16 + m] = __float2half(c1[r] * di);
    }
}

// ---------------------------------------------------------------------------
// Gather step helper: K parallel gathers (loads issued together, then summed)
// ---------------------------------------------------------------------------
template<int K>
__device__ __forceinline__ void gstep(const int* __restrict__ es,
                                      const __half2* __restrict__ rows,
                                      int cc, int e, float& a0, float& a1) {
    int s[K];
    float2 f[K];
#pragma unroll
    for (int k = 0; k < K; ++k) s[k] = es[e + k];
#pragma unroll
    for (int k = 0; k < K; ++k) f[k] = __half22float2(rows[s[k] * 16 + cc]);
#pragma unroll
    for (int k = 0; k < K; ++k) { a0 += f[k].x; a1 += f[k].y; }
}

// ---------------------------------------------------------------------------
// Fused gather, half2: 16 lanes per node x 2 cols. Main 16-unroll + binary
// tail ladder (8/4/2/1) so leftover edges don't serialize one latency each.
// Epilogue: self-loop + tanh + sorted-batch pool.
// ---------------------------------------------------------------------------
__global__ __launch_bounds__(256) void k_gather(const __half* __restrict__ xws,
                                                const float* __restrict__ dinv,
                                                const int* __restrict__ rowstart,
                                                const int* __restrict__ edge_src,
                                                const int* __restrict__ batch,
                                                const float* __restrict__ b1,
                                                float* __restrict__ sums) {
    const __half2* rows = (const __half2*)xws;   // row stride = 16 half2
    int grp = threadIdx.x >> 4;          // node slot 0..15
    int cc  = threadIdx.x & 15;          // half2 column
    int i = blockIdx.x * 16 + grp;
    float di = dinv[i];
    int e0 = rowstart[i], e1 = rowstart[i + 1];
    float a0 = 0.f, a1 = 0.f;
    int e = e0;
    for (; e + 16 <= e1; e += 16) gstep<16>(edge_src, rows, cc, e, a0, a1);
    if (e + 8 <= e1) { gstep<8>(edge_src, rows, cc, e, a0, a1); e += 8; }
    if (e + 4 <= e1) { gstep<4>(edge_src, rows, cc, e, a0, a1); e += 4; }
    if (e + 2 <= e1) { gstep<2>(edge_src, rows, cc, e, a0, a1); e += 2; }
    if (e < e1)      { gstep<1>(edge_src, rows, cc, e, a0, a1); }
    float2 fs = __half22float2(rows[i * 16 + cc]);
    float2 bb = *(const float2*)(b1 + 2 * cc);
    float h0 = tanhf((a0 + fs.x) * di + bb.x);
    float h1 = tanhf((a1 + fs.y) * di + bb.y);

    __shared__ float hs[16][EMB];
    __shared__ int gb[16];
    *(float2*)&hs[grp][2 * cc] = make_float2(h0, h1);
    if (cc == 0) gb[grp] = batch[i];
    __syncthreads();
    if (threadIdx.x < 32) {
        int col = threadIdx.x;
        int rr = 0;
        while (rr < 16) {
            int g0 = gb[rr];
            float a = hs[rr][col];
            int r2 = rr + 1;
            while (r2 < 16 && gb[r2] == g0) { a += hs[r2][col]; ++r2; }
            atomicAdd(&sums[g0 * EMB + col], a);
            rr = r2;
        }
    }
}

// ---------------------------------------------------------------------------
// head: out[g] = [sums, means] @ Wout + bout
// ---------------------------------------------------------------------------
__global__ __launch_bounds__(64) void k_out(const float* __restrict__ sums,
                                            const float* __restrict__ counts,
                                            const float* __restrict__ Wout,
                                            const float* __restrict__ bout,
                                            float* __restrict__ out) {
    int g = blockIdx.x * 64 + threadIdx.x;
    if (g >= NUM_GRAPHS) return;
    float inv = 1.0f / fmaxf(counts[g], 1.0f);
    float acc = bout[0];
#pragma unroll
    for (int c = 0; c < EMB; ++c) {
        float s = sums[g * EMB + c];
        acc += s * Wout[c] + s * inv * Wout[EMB + c];
    }
    out[g] = acc;
}

extern "C" void kernel_launch(void* const* d_in, const int* in_sizes, int n_in,
                              void* d_out, int out_size, void* d_ws, size_t ws_size,
                              hipStream_t stream) {
    const float* x     = (const float*)d_in[0];
    const int*   ei    = (const int*)d_in[1];   // [2, E]
    const int*   batch = (const int*)d_in[2];   // [N], sorted
    const float* W1    = (const float*)d_in[3];
    const float* b1    = (const float*)d_in[4];
    const float* Wout  = (const float*)d_in[5];
    const float* bout  = (const float*)d_in[6];
    float* out = (float*)d_out;

    // workspace (~33 MB)
    char* ws = (char*)d_ws;
    __half* xwh        = (__half*)ws;       ws += (size_t)N_NODES * EMB * sizeof(__half);  // 6.4 MB
    unsigned int* recs = (unsigned int*)ws; ws += (size_t)N_EDGES * sizeof(int);           // 12.8 MB
    int*   edge_src    = (int*)ws;          ws += (size_t)N_EDGES * sizeof(int);           // 12.8 MB
    int*   rowstart    = (int*)ws;          ws += (size_t)(N_NODES + 4) * sizeof(int);     // 0.4 MB
    float* dinv        = (float*)ws;        ws += (size_t)N_NODES * sizeof(float);         // 0.4 MB
    int*   chist       = (int*)ws;          ws += FB * sizeof(int);
    int*   cbase       = (int*)ws;          ws += (FB + 2) * sizeof(int);
    int*   gcursor     = (int*)ws;          ws += FB * sizeof(int);
    float* sums        = (float*)ws;        ws += (size_t)NUM_GRAPHS * EMB * sizeof(float);
    float* counts      = (float*)ws;

    hipMemsetAsync(chist, 0, FB * sizeof(int), stream);

    k_hist1 <<<H_BLOCKS, 256, 0, stream>>>(ei, chist);
    k_aux   <<<2, 512, 0, stream>>>(chist, cbase, gcursor, batch, sums, counts);
    k_fill1 <<<F1_BLOCKS, 512, 0, stream>>>(ei, gcursor, recs);
    k_fill2 <<<NBUCKETS, 512, 0, stream>>>(recs, cbase, edge_src, rowstart, dinv);
    k_xw    <<<XW_BLOCKS, 256, 0, stream>>>(x, W1, dinv, xwh);
    k_gather<<<N_NODES / 16, 256, 0, stream>>>(xwh, dinv, rowstart, edge_src, batch, b1, sums);
    k_out   <<<(NUM_GRAPHS + 63) / 64, 64, 0, stream>>>(sums, counts, Wout, bout, out);
}

// Round 10
// 228.630 us; speedup vs baseline: 3.8976x; 1.1575x over previous
//
#include <hip/hip_runtime.h>
#include <hip/hip_fp16.h>

#define N_NODES    100000
#define N_EDGES    3200000
#define IN_DIM     128
#define EMB        32
#define NUM_GRAPHS 256

#define FB         1024      // coarse buckets (782 used: bucket = dst >> 7)
#define NODES_PB   128       // nodes per bucket
#define NBUCKETS   782       // ceil(N_NODES / 128)
#define F1_EPB     20000     // edges per fill block
#define F1_BLOCKS  160       // 160 * 20000 == N_EDGES (atomic chain depth 160)
#define H_EPB      20000     // edges per hist block
#define H_BLOCKS   160
#define XW_BLOCKS  1563      // ceil(N_NODES / 64)
#define CAP        5632      // fill2 LDS staging (mean 4092, +24 sigma)

typedef _Float16 half8 __attribute__((ext_vector_type(8)));
typedef float floatx4 __attribute__((ext_vector_type(4)));

// ---------------------------------------------------------------------------
// Coarse histogram of dst>>7. 160 blocks ONLY: the global merge serializes
// per-address at ~40ns/atomic, so wall-clock ~ chain depth (= #blocks, since
// nearly every block touches every bucket). R9 measured 1563 blocks = 57.6us;
// 160 blocks -> ~6.4us chain.  chist pre-zeroed by memset.
// ---------------------------------------------------------------------------
__global__ __launch_bounds__(512) void k_hist1(const int* __restrict__ ei,
                                               int* __restrict__ chist) {
    __shared__ int h[FB];
    int t = threadIdx.x;
    for (int i = t; i < FB; i += 512) h[i] = 0;
    __syncthreads();
    int e0 = blockIdx.x * H_EPB;
    int e1 = e0 + H_EPB; if (e1 > N_EDGES) e1 = N_EDGES;
    for (int e = e0 + t; e < e1; e += 512)
        atomicAdd(&h[ei[N_EDGES + e] >> 7], 1);
    __syncthreads();
    for (int i = t; i < FB; i += 512)
        if (h[i]) atomicAdd(&chist[i], h[i]);
}

// ---------------------------------------------------------------------------
// Aux (2 blocks x 512): block 0 = exclusive scan of chist[1024] (2 elems per
// thread) -> cbase[1025] + gcursor; block 1 = zero sums + per-graph counts.
// ---------------------------------------------------------------------------
__global__ __launch_bounds__(512) void k_aux(const int* __restrict__ chist,
                                             int* __restrict__ cbase,
                                             int* __restrict__ gcursor,
                                             const int* __restrict__ batch,
                                             float* __restrict__ sums,
                                             float* __restrict__ counts) {
    int t = threadIdx.x;
    if (blockIdx.x == 0) {
        __shared__ int ts[512];
        int v0 = chist[2 * t], v1 = chist[2 * t + 1];
        int tot = v0 + v1;
        ts[t] = tot;
        __syncthreads();
        for (int off = 1; off < 512; off <<= 1) {
            int u = (t >= off) ? ts[t - off] : 0;
            __syncthreads();
            ts[t] += u;
            __syncthreads();
        }
        int base = ts[t] - tot;
        cbase[2 * t] = base;          gcursor[2 * t] = base;
        cbase[2 * t + 1] = base + v0; gcursor[2 * t + 1] = base + v0;
        if (t == 511) cbase[FB] = ts[511];
    } else {
        for (int i = t; i < NUM_GRAPHS * EMB; i += 512) sums[i] = 0.f;
        if (t < NUM_GRAPHS) {
            int lo = 0, hi = N_NODES;
            while (lo < hi) { int mid = (lo + hi) >> 1; if (batch[mid] < t) lo = mid + 1; else hi = mid; }
            int a = lo;
            lo = 0; hi = N_NODES;
            int g1 = t + 1;
            while (lo < hi) { int mid = (lo + hi) >> 1; if (batch[mid] < g1) lo = mid + 1; else hi = mid; }
            counts[t] = (float)(lo - a);
        }
    }
}

// ---------------------------------------------------------------------------
// Fill1: group edges by bucket (dst>>7), direct global placement. 160 blocks
// (reservation chain 160 x 40ns). Two passes over the edge slice (re-read ei
// instead of register-buffering: +2us aggregate IO, no VGPR pressure).
// rec = (dst&127)<<24 | src.  Runs ~25.6 recs (~102B) -> writeback ~ payload.
// ---------------------------------------------------------------------------
__global__ __launch_bounds__(512) void k_fill1(const int* __restrict__ ei,
                                               int* __restrict__ gcursor,
                                               unsigned int* __restrict__ recs) {
    __shared__ int hist[FB];
    __shared__ int base[FB];
    __shared__ int lcur[FB];
    int t = threadIdx.x;
    for (int i = t; i < FB; i += 512) { hist[i] = 0; lcur[i] = 0; }
    __syncthreads();
    int e0 = blockIdx.x * F1_EPB;
    int e1 = e0 + F1_EPB; if (e1 > N_EDGES) e1 = N_EDGES;
    for (int e = e0 + t; e < e1; e += 512)
        atomicAdd(&hist[ei[N_EDGES + e] >> 7], 1);
    __syncthreads();
    for (int i = t; i < FB; i += 512)
        if (hist[i]) base[i] = atomicAdd(&gcursor[i], hist[i]);
    __syncthreads();
    for (int e = e0 + t; e < e1; e += 512) {
        int s = ei[e];
        int d = ei[N_EDGES + e];
        int b = d >> 7;
        int pos = base[b] + atomicAdd(&lcur[b], 1);
        recs[pos] = ((unsigned int)(d & 127) << 24) | (unsigned int)s;
    }
}

// ---------------------------------------------------------------------------
// Fill2: one block per 128-node bucket (782 blocks, ~24 KB LDS -> 6/CU).
// LDS histogram of bucket's recs -> deg -> rowstart + dinv + cursors; staged
// counting sort emits edge_src.
// ---------------------------------------------------------------------------
__global__ __launch_bounds__(512) void k_fill2(const unsigned int* __restrict__ recs,
                                               const int* __restrict__ cbase,
                                               int* __restrict__ edge_src,
                                               int* __restrict__ rowstart,
                                               float* __restrict__ dinv) {
    __shared__ unsigned int lbuf[CAP];          // 22 KB
    __shared__ int h2[NODES_PB], cur2[NODES_PB], sc[NODES_PB];
    int t = threadIdx.x, b = blockIdx.x;
    if (t < NODES_PB) h2[t] = 0;
    __syncthreads();
    int seg0 = cbase[b];
    int cnt = cbase[b + 1] - seg0;
    for (int j = t; j < cnt; j += 512) {
        unsigned int r = recs[seg0 + j];
        if (j < CAP) lbuf[j] = r;
        atomicAdd(&h2[r >> 24], 1);
    }
    __syncthreads();
    int v = 0;
    if (t < NODES_PB) { v = h2[t]; sc[t] = v; }
    __syncthreads();
    for (int off = 1; off < NODES_PB; off <<= 1) {
        int u = 0;
        if (t < NODES_PB && t >= off) u = sc[t - off];
        __syncthreads();
        if (t < NODES_PB) sc[t] += u;
        __syncthreads();
    }
    int node0 = b << 7;
    if (t < NODES_PB) {
        int excl = sc[t] - v;
        cur2[t] = excl;
        int node = node0 + t;
        if (node < N_NODES) {
            rowstart[node] = seg0 + excl;
            dinv[node] = rsqrtf((float)v + 1.0f);
        }
    }
    if (b == 0 && t == 0) rowstart[N_NODES] = N_EDGES;
    __syncthreads();
    for (int j = t; j < cnt; j += 512) {
        unsigned int r = (j < CAP) ? lbuf[j] : recs[seg0 + j];
        int p = atomicAdd(&cur2[r >> 24], 1);
        edge_src[seg0 + p] = (int)(r & 0x00FFFFFF);
    }
}

// ---------------------------------------------------------------------------
// xw = (x @ W1) * dinv[row] -> fp16 via MFMA 16x16x32_f16 (one wave = 16
// rows). Runs AFTER fill2 so the dinv scale folds in here. Wh padded to
// stride 33 -> bfrag reads conflict-free.
// ---------------------------------------------------------------------------
__global__ __launch_bounds__(256) void k_xw(const float* __restrict__ x,
                                            const float* __restrict__ W1,
                                            const float* __restrict__ dinv,
                                            __half* __restrict__ xwh) {
    __shared__ _Float16 Wh[IN_DIM * (EMB + 1)];   // 8.25 KB, padded stride 33
    for (int i = threadIdx.x; i < IN_DIM * EMB; i += 256)
        Wh[(i >> 5) * (EMB + 1) + (i & 31)] = (_Float16)W1[i];
    __syncthreads();
    int wave = threadIdx.x >> 6;
    int lane = threadIdx.x & 63;
    int m = lane & 15, quad = lane >> 4;
    int row0 = (blockIdx.x * 4 + wave) * 16;
    if (row0 >= N_NODES) return;
    half8 bfrag[2][4];
#pragma unroll
    for (int nt = 0; nt < 2; ++nt)
#pragma unroll
        for (int ks = 0; ks < 4; ++ks)
#pragma unroll
            for (int j = 0; j < 8; ++j)
                bfrag[nt][ks][j] = Wh[(ks * 32 + quad * 8 + j) * (EMB + 1) + nt * 16 + m];
    const float* xr = x + (size_t)(row0 + m) * IN_DIM + quad * 8;
    floatx4 c0 = {0.f, 0.f, 0.f, 0.f}, c1 = {0.f, 0.f, 0.f, 0.f};
#pragma unroll
    for (int ks = 0; ks < 4; ++ks) {
        float4 a0 = *(const float4*)(xr + ks * 32);
        float4 a1 = *(const float4*)(xr + ks * 32 + 4);
        half8 af;
        af[0] = (_Float16)a0.x; af[1] = (_Float16)a0.y;
        af[2] = (_Float16)a0.z; af[3] = (_Float16)a0.w;
        af[4] = (_Float16)a1.x; af[5] = (_Float16)a1.y;
        af[6] = (_Float16)a1.z; af[7] = (_Float16)a1.w;
        c0 = __builtin_amdgcn_mfma_f32_16x16x32_f16(af, bfrag[0][ks], c0, 0, 0, 0);
        c1 = __builtin_amdgcn_mfma_f32_16x16x32_f16(af, bfrag[1][ks], c1, 0, 0, 0);
    }
#pragma unroll
    for (int r = 0; r < 4; ++r) {
        int ro = row0 + quad * 4 + r;
        float di = dinv[ro];
        xwh[(size_t)ro * EMB + m]      = __float2half(c0[r] * di);
        xwh[(size_t)ro * EMB + 16 + m] = __float2half(c1[r] * di);
    }
}

// ---------------------------------------------------------------------------
// Gather step helper: K parallel gathers (loads issued together, then summed)
// ---------------------------------------------------------------------------
template<int K>
__device__ __forceinline__ void gstep(const int* __restrict__ es,
                                      const __half2* __restrict__ rows,
                                      int cc, int e, float& a0, float& a1) {
    int s[K];
    float2 f[K];
#pragma unroll
    for (int k = 0; k < K; ++k) s[k] = es[e + k];
#pragma unroll
    for (int k = 0; k < K; ++k) f[k] = __half22float2(rows[s[k] * 16 + cc]);
#pragma unroll
    for (int k = 0; k < K; ++k) { a0 += f[k].x; a1 += f[k].y; }
}

// ---------------------------------------------------------------------------
// Fused gather, half2: 16 lanes per node x 2 cols. Main 16-unroll + binary
// tail ladder. Epilogue: self-loop + tanh + sorted-batch pool.
// ---------------------------------------------------------------------------
__global__ __launch_bounds__(256) void k_gather(const __half* __restrict__ xws,
                                                const float* __restrict__ dinv,
                                                const int* __restrict__ rowstart,
                                                const int* __restrict__ edge_src,
                                                const int* __restrict__ batch,
                                                const float* __restrict__ b1,
                                                float* __restrict__ sums) {
    const __half2* rows = (const __half2*)xws;   // row stride = 16 half2
    int grp = threadIdx.x >> 4;          // node slot 0..15
    int cc  = threadIdx.x & 15;          // half2 column
    int i = blockIdx.x * 16 + grp;
    float di = dinv[i];
    int e0 = rowstart[i], e1 = rowstart[i + 1];
    float a0 = 0.f, a1 = 0.f;
    int e = e0;
    for (; e + 16 <= e1; e += 16) gstep<16>(edge_src, rows, cc, e, a0, a1);
    if (e + 8 <= e1) { gstep<8>(edge_src, rows, cc, e, a0, a1); e += 8; }
    if (e + 4 <= e1) { gstep<4>(edge_src, rows, cc, e, a0, a1); e += 4; }
    if (e + 2 <= e1) { gstep<2>(edge_src, rows, cc, e, a0, a1); e += 2; }
    if (e < e1)      { gstep<1>(edge_src, rows, cc, e, a0, a1); }
    float2 fs = __half22float2(rows[i * 16 + cc]);
    float2 bb = *(const float2*)(b1 + 2 * cc);
    float h0 = tanhf((a0 + fs.x) * di + bb.x);
    float h1 = tanhf((a1 + fs.y) * di + bb.y);

    __shared__ float hs[16][EMB];
    __shared__ int gb[16];
    *(float2*)&hs[grp][2 * cc] = make_float2(h0, h1);
    if (cc == 0) gb[grp] = batch[i];
    __syncthreads();
    if (threadIdx.x < 32) {
        int col = threadIdx.x;
        int rr = 0;
        while (rr < 16) {
            int g0 = gb[rr];
            float a = hs[rr][col];
            int r2 = rr + 1;
            while (r2 < 16 && gb[r2] == g0) { a += hs[r2][col]; ++r2; }
            atomicAdd(&sums[g0 * EMB + col], a);
            rr = r2;
        }
    }
}

// ---------------------------------------------------------------------------
// head: out[g] = [sums, means] @ Wout + bout
// ---------------------------------------------------------------------------
__global__ __launch_bounds__(64) void k_out(const float* __restrict__ sums,
                                            const float* __restrict__ counts,
                                            const float* __restrict__ Wout,
                                            const float* __restrict__ bout,
                                            float* __restrict__ out) {
    int g = blockIdx.x * 64 + threadIdx.x;
    if (g >= NUM_GRAPHS) return;
    float inv = 1.0f / fmaxf(counts[g], 1.0f);
    float acc = bout[0];
#pragma unroll
    for (int c = 0; c < EMB; ++c) {
        float s = sums[g * EMB + c];
        acc += s * Wout[c] + s * inv * Wout[EMB + c];
    }
    out[g] = acc;
}

extern "C" void kernel_launch(void* const* d_in, const int* in_sizes, int n_in,
                              void* d_out, int out_size, void* d_ws, size_t ws_size,
                              hipStream_t stream) {
    const float* x     = (const float*)d_in[0];
    const int*   ei    = (const int*)d_in[1];   // [2, E]
    const int*   batch = (const int*)d_in[2];   // [N], sorted
    const float* W1    = (const float*)d_in[3];
    const float* b1    = (const float*)d_in[4];
    const float* Wout  = (const float*)d_in[5];
    const float* bout  = (const float*)d_in[6];
    float* out = (float*)d_out;

    // workspace (~33 MB)
    char* ws = (char*)d_ws;
    __half* xwh        = (__half*)ws;       ws += (size_t)N_NODES * EMB * sizeof(__half);  // 6.4 MB
    unsigned int* recs = (unsigned int*)ws; ws += (size_t)N_EDGES * sizeof(int);           // 12.8 MB
    int*   edge_src    = (int*)ws;          ws += (size_t)N_EDGES * sizeof(int);           // 12.8 MB
    int*   rowstart    = (int*)ws;          ws += (size_t)(N_NODES + 4) * sizeof(int);     // 0.4 MB
    float* dinv        = (float*)ws;        ws += (size_t)N_NODES * sizeof(float);         // 0.4 MB
    int*   chist       = (int*)ws;          ws += FB * sizeof(int);
    int*   cbase       = (int*)ws;          ws += (FB + 2) * sizeof(int);
    int*   gcursor     = (int*)ws;          ws += FB * sizeof(int);
    float* sums        = (float*)ws;        ws += (size_t)NUM_GRAPHS * EMB * sizeof(float);
    float* counts      = (float*)ws;

    hipMemsetAsync(chist, 0, FB * sizeof(int), stream);

    k_hist1 <<<H_BLOCKS, 512, 0, stream>>>(ei, chist);
    k_aux   <<<2, 512, 0, stream>>>(chist, cbase, gcursor, batch, sums, counts);
    k_fill1 <<<F1_BLOCKS, 512, 0, stream>>>(ei, gcursor, recs);
    k_fill2 <<<NBUCKETS, 512, 0, stream>>>(recs, cbase, edge_src, rowstart, dinv);
    k_xw    <<<XW_BLOCKS, 256, 0, stream>>>(x, W1, dinv, xwh);
    k_gather<<<N_NODES / 16, 256, 0, stream>>>(xwh, dinv, rowstart, edge_src, batch, b1, sums);
    k_out   <<<(NUM_GRAPHS + 63) / 64, 64, 0, stream>>>(sums, counts, Wout, bout, out);
}